// Round 3
// baseline (168.530 us; speedup 1.0000x reference)
//
#include <hip/hip_runtime.h>

// Problem: B=16, C=4, H=W=512. input [B,C,H,W] f32; target [B,C+1,H,W] f32,
// last channel a {0,1} mask. Output scalar:
//   (1/B) * sum_b [ cnt_b>0 ? sum_{c,hw} mask*(in-tg)^2 / (C*cnt_b) : 0 ]
//
// History: R7 (166.0): 3 streams/block, one channel per block, XCD-swizzled
// mask reuse, nontemporal in/tg loads, memset+atomics. R8 (160.1): dropped
// memset node + atomics for per-block ws slots, parallel final reduce.
// R9 (156.3): occupancy attack — 2048 blocks (8/CU), 6-load groups,
// launch_bounds(256,8) -> 32 waves/CU. Only -3.7 us => NOT latency-bound;
// read path capped at ~3.4 TB/s by something else.
// R10 (this round): single-variable A/B — remove __builtin_nontemporal_load
// from in/tg streams (nt was introduced in R7 bundled with the 3-stream
// restructure, never ablated alone). Theory: nt read policy throttles the
// L2-side read path; plain coalesced dwordx4 reads should stream at
// ~BabelStream-read rates. Everything else byte-identical to R9.

#define BATCH 16
#define CHAN 4
#define HWPIX (512 * 512)                 // 262144 pixels per plane
#define CHUNK_PX 8192                     // pixels per chunk
#define CPB (HWPIX / CHUNK_PX)            // 32 chunks per plane
#define UNITS (BATCH * CPB)               // 512 (b,k) units
#define THREADS 256
#define TOTAL_BLOCKS (UNITS * CHAN)       // 2048 blocks = 8 per CU
#define G4 (CHUNK_PX / 4)                 // 2048 float4 per chunk-plane
#define ITERS (G4 / THREADS)              // 8 iterations per thread

// ws layout: [0, 2048)        S slot per block  at (b*4 + c)*32 + k
//            [2048, 2048+512) cnt slot per unit at b*32 + k   (c==0 blocks)
#define WS_CNT_BASE (UNITS * CHAN)

typedef float vf4 __attribute__((ext_vector_type(4)));

__global__ __launch_bounds__(THREADS, 8) void masked_mse_partial(
    const float* __restrict__ input,
    const float* __restrict__ target,
    float* __restrict__ ws) {
    // blockIdx swizzle: idx = q*32 + c*8 + r. All four c-blocks of unit
    // u=(q,r) are congruent mod 8 -> same XCD, dispatched within a 32-block
    // window -> mask chunk L2-hits on 3 of 4 reads.
    const int bid = blockIdx.x;
    const int r   = bid & 7;
    const int c   = (bid >> 3) & 3;
    const int q   = bid >> 5;             // [0, 64)
    const int u   = q * 8 + r;            // [0, 512)
    const int b   = u >> 5;               // u / CPB
    const int k   = u & (CPB - 1);

    const vf4* ip = (const vf4*)(input  + ((size_t)b * CHAN + c) * HWPIX
                                        + (size_t)k * CHUNK_PX);
    const vf4* tp = (const vf4*)(target + ((size_t)b * (CHAN + 1) + c) * HWPIX
                                        + (size_t)k * CHUNK_PX);
    const vf4* mp = (const vf4*)(target + ((size_t)b * (CHAN + 1) + CHAN) * HWPIX
                                        + (size_t)k * CHUNK_PX);

    float s = 0.f, cnt = 0.f;

    // 6 grouped loads (2 iters x 3 streams) in flight -> ~24 data VGPRs,
    // VGPR <= 64 so 8 waves/SIMD resident. TLP does the latency hiding.
    // R10: plain loads (nt removed — A/B vs R9).
    for (int it = 0; it < ITERS; it += 2) {
        const int g0 = it * THREADS + threadIdx.x;
        vf4 a0 = ip[g0];
        vf4 a1 = ip[g0 + THREADS];
        vf4 t0 = tp[g0];
        vf4 t1 = tp[g0 + THREADS];
        vf4 m0 = mp[g0];
        vf4 m1 = mp[g0 + THREADS];

        vf4 d0 = a0 - t0, d1 = a1 - t1;
        vf4 acc = d0 * d0 * m0 + d1 * d1 * m1;
        s += acc.x + acc.y + acc.z + acc.w;

        if (c == 0) {   // wave-uniform: count mask once per (b,k) unit
            vf4 mc = m0 + m1;
            cnt += mc.x + mc.y + mc.z + mc.w;
        }
    }

    // wave-64 shuffle reduction
#pragma unroll
    for (int off = 32; off > 0; off >>= 1) {
        s   += __shfl_down(s, off, 64);
        cnt += __shfl_down(cnt, off, 64);
    }

    __shared__ float ss[THREADS / 64];
    __shared__ float sc[THREADS / 64];
    const int lane = threadIdx.x & 63;
    const int wid  = threadIdx.x >> 6;
    if (lane == 0) { ss[wid] = s; sc[wid] = cnt; }
    __syncthreads();

    if (threadIdx.x == 0) {
        float S = 0.f, Cn = 0.f;
#pragma unroll
        for (int w = 0; w < THREADS / 64; ++w) { S += ss[w]; Cn += sc[w]; }
        // unique slot per block -> no memset, no atomics, poison-safe
        ws[(b * CHAN + c) * CPB + k] = S;
        if (c == 0) ws[WS_CNT_BASE + b * CPB + k] = Cn;
    }
}

__global__ __launch_bounds__(256) void masked_mse_final(
    const float* __restrict__ ws,
    float* __restrict__ out) {
    // 256 threads = 16 groups of 16 lanes; group g handles batch b=g.
    // Each batch has 128 S slots (4 c * 32 k) and 32 cnt slots.
    const int t = threadIdx.x;
    const int g = t >> 4;                 // batch
    const int j = t & 15;

    float S = 0.f;
#pragma unroll
    for (int i = 0; i < 8; ++i) S += ws[g * 128 + j * 8 + i];
    float Cn = ws[WS_CNT_BASE + g * 32 + j * 2]
             + ws[WS_CNT_BASE + g * 32 + j * 2 + 1];

    // reduce within each 16-lane group (all inside one wave-64)
#pragma unroll
    for (int off = 8; off > 0; off >>= 1) {
        S  += __shfl_down(S,  off, 16);
        Cn += __shfl_down(Cn, off, 16);
    }

    __shared__ float per_b[BATCH];
    if (j == 0) {
        float cb = Cn * (float)CHAN;      // C * #masked pixels
        per_b[g] = (cb > 0.f) ? (S / cb) : 0.f;
    }
    __syncthreads();

    if (t == 0) {
        float acc = 0.f;
#pragma unroll
        for (int b = 0; b < BATCH; ++b) acc += per_b[b];
        out[0] = acc / (float)BATCH;
    }
}

extern "C" void kernel_launch(void* const* d_in, const int* in_sizes, int n_in,
                              void* d_out, int out_size, void* d_ws, size_t ws_size,
                              hipStream_t stream) {
    const float* input  = (const float*)d_in[0];
    const float* target = (const float*)d_in[1];
    float* out = (float*)d_out;
    float* ws  = (float*)d_ws;

    masked_mse_partial<<<dim3(TOTAL_BLOCKS), dim3(THREADS), 0, stream>>>(
        input, target, ws);
    masked_mse_final<<<1, 256, 0, stream>>>(ws, out);
}

// Round 4
// 155.886 us; speedup vs baseline: 1.0811x; 1.0811x over previous
//
#include <hip/hip_runtime.h>

// Problem: B=16, C=4, H=W=512. input [B,C,H,W] f32; target [B,C+1,H,W] f32,
// last channel a {0,1} mask. Output scalar:
//   (1/B) * sum_b [ cnt_b>0 ? sum_{c,hw} mask*(in-tg)^2 / (C*cnt_b) : 0 ]
//
// History: R7 (166.0): 3 streams/block, XCD-swizzled mask reuse, nt in/tg.
// R8 (160.1): no memset/atomics, per-block ws slots. R9 (156.3): 2048
// blocks (8/CU), 6-load groups, 32 waves/CU. R10 (168.5): nt removed ->
// partial 44->56.5 us REGRESSION; proved nt is load-bearing (+22% read
// path). R10 counters: FETCH 73.75 MB of 151 MB logical (half LLC-hit),
// VALUBusy 3.6%, HBM 16% -> limiter is per-CU outstanding-read capacity
// (~5.6 B/cyc/CU = MSHR x 64B / ~675cyc avg latency); burst depth and
// occupancy already shown neutral.
// R11 (this round): revert to R9 (nt on in/tg) + ONE delta: mask loads nt
// too. Theory: nt benefit is per-request-path; mask is the remaining 1/3
// of load instrs. nt still allocates in L2 (evict-first) so the
// 32-block-window mask reuse should survive. Falsifier: FETCH +30-50 MB.

#define BATCH 16
#define CHAN 4
#define HWPIX (512 * 512)                 // 262144 pixels per plane
#define CHUNK_PX 8192                     // pixels per chunk
#define CPB (HWPIX / CHUNK_PX)            // 32 chunks per plane
#define UNITS (BATCH * CPB)               // 512 (b,k) units
#define THREADS 256
#define TOTAL_BLOCKS (UNITS * CHAN)       // 2048 blocks = 8 per CU
#define G4 (CHUNK_PX / 4)                 // 2048 float4 per chunk-plane
#define ITERS (G4 / THREADS)              // 8 iterations per thread

// ws layout: [0, 2048)        S slot per block  at (b*4 + c)*32 + k
//            [2048, 2048+512) cnt slot per unit at b*32 + k   (c==0 blocks)
#define WS_CNT_BASE (UNITS * CHAN)

typedef float vf4 __attribute__((ext_vector_type(4)));

__global__ __launch_bounds__(THREADS, 8) void masked_mse_partial(
    const float* __restrict__ input,
    const float* __restrict__ target,
    float* __restrict__ ws) {
    // blockIdx swizzle: idx = q*32 + c*8 + r. All four c-blocks of unit
    // u=(q,r) are congruent mod 8 -> same XCD, dispatched within a 32-block
    // window -> mask chunk L2-hits on 3 of 4 reads.
    const int bid = blockIdx.x;
    const int r   = bid & 7;
    const int c   = (bid >> 3) & 3;
    const int q   = bid >> 5;             // [0, 64)
    const int u   = q * 8 + r;            // [0, 512)
    const int b   = u >> 5;               // u / CPB
    const int k   = u & (CPB - 1);

    const vf4* ip = (const vf4*)(input  + ((size_t)b * CHAN + c) * HWPIX
                                        + (size_t)k * CHUNK_PX);
    const vf4* tp = (const vf4*)(target + ((size_t)b * (CHAN + 1) + c) * HWPIX
                                        + (size_t)k * CHUNK_PX);
    const vf4* mp = (const vf4*)(target + ((size_t)b * (CHAN + 1) + CHAN) * HWPIX
                                        + (size_t)k * CHUNK_PX);

    float s = 0.f, cnt = 0.f;

    // 6 grouped loads (2 iters x 3 streams) in flight -> ~24 data VGPRs,
    // VGPR <= 64 so 8 waves/SIMD resident. All three streams nt (R11).
    for (int it = 0; it < ITERS; it += 2) {
        const int g0 = it * THREADS + threadIdx.x;
        vf4 a0 = __builtin_nontemporal_load(&ip[g0]);
        vf4 a1 = __builtin_nontemporal_load(&ip[g0 + THREADS]);
        vf4 t0 = __builtin_nontemporal_load(&tp[g0]);
        vf4 t1 = __builtin_nontemporal_load(&tp[g0 + THREADS]);
        vf4 m0 = __builtin_nontemporal_load(&mp[g0]);
        vf4 m1 = __builtin_nontemporal_load(&mp[g0 + THREADS]);

        vf4 d0 = a0 - t0, d1 = a1 - t1;
        vf4 acc = d0 * d0 * m0 + d1 * d1 * m1;
        s += acc.x + acc.y + acc.z + acc.w;

        if (c == 0) {   // wave-uniform: count mask once per (b,k) unit
            vf4 mc = m0 + m1;
            cnt += mc.x + mc.y + mc.z + mc.w;
        }
    }

    // wave-64 shuffle reduction
#pragma unroll
    for (int off = 32; off > 0; off >>= 1) {
        s   += __shfl_down(s, off, 64);
        cnt += __shfl_down(cnt, off, 64);
    }

    __shared__ float ss[THREADS / 64];
    __shared__ float sc[THREADS / 64];
    const int lane = threadIdx.x & 63;
    const int wid  = threadIdx.x >> 6;
    if (lane == 0) { ss[wid] = s; sc[wid] = cnt; }
    __syncthreads();

    if (threadIdx.x == 0) {
        float S = 0.f, Cn = 0.f;
#pragma unroll
        for (int w = 0; w < THREADS / 64; ++w) { S += ss[w]; Cn += sc[w]; }
        // unique slot per block -> no memset, no atomics, poison-safe
        ws[(b * CHAN + c) * CPB + k] = S;
        if (c == 0) ws[WS_CNT_BASE + b * CPB + k] = Cn;
    }
}

__global__ __launch_bounds__(256) void masked_mse_final(
    const float* __restrict__ ws,
    float* __restrict__ out) {
    // 256 threads = 16 groups of 16 lanes; group g handles batch b=g.
    // Each batch has 128 S slots (4 c * 32 k) and 32 cnt slots.
    const int t = threadIdx.x;
    const int g = t >> 4;                 // batch
    const int j = t & 15;

    float S = 0.f;
#pragma unroll
    for (int i = 0; i < 8; ++i) S += ws[g * 128 + j * 8 + i];
    float Cn = ws[WS_CNT_BASE + g * 32 + j * 2]
             + ws[WS_CNT_BASE + g * 32 + j * 2 + 1];

    // reduce within each 16-lane group (all inside one wave-64)
#pragma unroll
    for (int off = 8; off > 0; off >>= 1) {
        S  += __shfl_down(S,  off, 16);
        Cn += __shfl_down(Cn, off, 16);
    }

    __shared__ float per_b[BATCH];
    if (j == 0) {
        float cb = Cn * (float)CHAN;      // C * #masked pixels
        per_b[g] = (cb > 0.f) ? (S / cb) : 0.f;
    }
    __syncthreads();

    if (t == 0) {
        float acc = 0.f;
#pragma unroll
        for (int b = 0; b < BATCH; ++b) acc += per_b[b];
        out[0] = acc / (float)BATCH;
    }
}

extern "C" void kernel_launch(void* const* d_in, const int* in_sizes, int n_in,
                              void* d_out, int out_size, void* d_ws, size_t ws_size,
                              hipStream_t stream) {
    const float* input  = (const float*)d_in[0];
    const float* target = (const float*)d_in[1];
    float* out = (float*)d_out;
    float* ws  = (float*)d_ws;

    masked_mse_partial<<<dim3(TOTAL_BLOCKS), dim3(THREADS), 0, stream>>>(
        input, target, ws);
    masked_mse_final<<<1, 256, 0, stream>>>(ws, out);
}